// Round 3
// baseline (132.016 us; speedup 1.0000x reference)
//
#include <hip/hip_runtime.h>
#include <math.h>

// GEBLNet via Gram-matrix reduction.
// R20 = R19 restructured as 2 INDEPENDENT waves per workgroup (128 thr).
// Rationale: occupancy pinned at ~11.5 waves/CU across {LDS 10240/8192} x
// {VGPR 44/52/64} -> the cap is per-WORKGROUP (CU wg slots / dispatch
// watermark), not LDS/VGPR. Packing 2 independent points per wg doubles
// waves/CU at the same wg count. Each wave owns its LDS slice; the shared
// __syncthreads() is uniform and identical-length across both waves (skew~0).
// NOT a repeat of R12's regression: there, waves COOPERATED on one point
// (imbalance + barrier serialization); here waves are fully independent.
// Inner loops byte-identical to R19 for clean attribution.
// R19 lessons: 2a unroll-2 + phase-5 unroll-4 ILP = -8.8us; VGPR 64 ok.
// R18 lessons: LDS bank conflicts fixed (98K); union overlay sound.
// LESSON (R16): full merge of 2a+2b -> VGPR 84 -> regress.
// LESSON (R15): fine-grained 1-cmac jobs beat wider jobs.
// LESSON (R11): direct-w2 contraction regresses. LESSON (R4+R7):
// launch_bounds min-waves arg -> spill. LESSON (R6): never
// reinterpret-cast local arrays.

#define NPTS 8192
#define THRESH 0.001f

__global__ void geblnet_setup(const float* __restrict__ w2,
                              float4* __restrict__ CTt) {
    int j = blockIdx.x * blockDim.x + threadIdx.x;
    if (j >= 12 * 169) return;
    int u = j / 169, it = j % 169;
    const float* W = w2 + u * 25 * 25 * 2;
#define WR(v, w) W[((v) * 25 + (w)) * 2]
#define WI(v, w) W[((v) * 25 + (w)) * 2 + 1]
    float c0, c1, c2, c3;
    if (it < 78) {                       // S pairs, a<=b
        int q = it, a = 0;
        while (q >= 12 - a) { q -= 12 - a; ++a; }
        int b = a + q;
        float ar = WR(a, b) + (a != b ? WR(b, a) : 0.f);
        float ai = WI(a, b) + (a != b ? WI(b, a) : 0.f);
        float br = WR(12 + a, 12 + b) + (a != b ? WR(12 + b, 12 + a) : 0.f);
        float bi = WI(12 + a, 12 + b) + (a != b ? WI(12 + b, 12 + a) : 0.f);
        c0 = ar + br; c1 = bi - ai; c2 = ai + bi; c3 = ar - br;
    } else if (it < 156) {               // Hm pairs, a<=b
        int q = it - 78, a = 0;
        while (q >= 12 - a) { q -= 12 - a; ++a; }
        int b = a + q;
        if (a != b) {
            float gr = WR(a, 12 + b) + WR(12 + b, a);
            float gi = WI(a, 12 + b) + WI(12 + b, a);
            float dr = WR(b, 12 + a) + WR(12 + a, b);
            float di = WI(b, 12 + a) + WI(12 + a, b);
            c0 = gr + dr; c1 = di - gi; c2 = gi + di; c3 = gr - dr;
        } else {
            float er = WR(a, 12 + a) + WR(12 + a, a);
            float ei = WI(a, 12 + a) + WI(12 + a, a);
            c0 = er; c1 = 0.f; c2 = ei; c3 = 0.f;
        }
    } else if (it < 168) {               // trace terms
        int a = it - 156;
        float fr = WR(a, 24) + WR(24, a), fi = WI(a, 24) + WI(24, a);
        float pr = WR(12 + a, 24) + WR(24, 12 + a);
        float pi = WI(12 + a, 24) + WI(24, 12 + a);
        c0 = fr + pr; c1 = pi - fi; c2 = fi + pi; c3 = fr - pr;
    } else {                             // unit-unit
        c0 = 3.f * WR(24, 24); c1 = 0.f; c2 = 3.f * WI(24, 24); c3 = 0.f;
    }
    CTt[it * 12 + u] = make_float4(c0, c1, c2, c3);
#undef WR
#undef WI
}

// Scratch union: Bs is dead after phase 2b; phase-3..6 scratch reuses it.
union Scr {
    float2 bs[702];                     // B[uu][v][jk], rows exact 9 (5616 B)
    struct {
        float2 tpar[60];                // phase 5 partials
        float2 tr1[12];                 // traces (layer 1, reused layer 2)
        float  sc1[12];                 // combined gerelu+trnorm scale
        float  gb[12];
        float  tra[12];
    } s;
};

__global__ __launch_bounds__(128) void geblnet_main(
    const float2* __restrict__ x2,      // (8192, 10, 9) complex
    const float2* __restrict__ w1g,     // (12,13,13) complex
    const float* __restrict__ dw,       // (24,)
    const float* __restrict__ db,       // (1,)
    const float4* __restrict__ CTt,     // (169,12)
    float* __restrict__ out)            // (8192,)
{
    // Per-wave LDS slices; overlay: phases 1-2 = We row-major (stride 10);
    //          phases 4-5 = GV[169].
    __shared__ float2 WeGV_[2][170];    // 2720 B
    __shared__ Scr S_[2];               // 11232 B
    __shared__ float2 Hs_[2][108];      // 1728 B
    // total 15680 B -> 16384 alloc -> 10 blocks/CU by LDS (20 waves)

    const int wid = threadIdx.x >> 6;
    const int t = threadIdx.x & 63;
    const int p = blockIdx.x * 2 + wid;

    float2* WeGV = WeGV_[wid];
    Scr* Sp = &S_[wid];
    float2* Hs = Hs_[wid];

    // ---- phase 1: build We channels 0..12, row-major only
    for (int j = t; j < 117; j += 64) {
        int v = j / 9, ik = j - v * 9;
        int i = ik / 3, jj = ik - i * 3;
        float2 val;
        if (v < 6) val = x2[(size_t)p * 90 + (4 + v) * 9 + ik];
        else if (v < 12) {
            float2 s = x2[(size_t)p * 90 + (v - 2) * 9 + jj * 3 + i];
            val = make_float2(s.x, -s.y);
        } else val = make_float2((i == jj) ? 1.f : 0.f, 0.f);
        WeGV[v * 10 + ik] = val;
    }
    __syncthreads();

    // ---- phase 2: layer 1 on all 64 lanes, two u-half passes
    #pragma unroll 1
    for (int g = 0; g < 2; ++g) {
        const int u0 = g * 6;
        // 2a: B[uu][v][jk] = sum_w w1[u0+uu,v,w] * We[w][jk]
        //     We read is per-w broadcast (addr depends only on jk): no
        //     bank conflicts. Incremental (uu,rem): e starts at t<117.
        {
            int uu = 0, rem = t;
            #pragma unroll 2
            for (int e = t; e < 702; e += 64) {
                int v = rem / 9, jk = rem - v * 9;
                const float2* cp = w1g + ((u0 + uu) * 13 + v) * 13; // contiguous
                float br = 0.f, bi = 0.f;
                #pragma unroll
                for (int w = 0; w < 13; ++w) {
                    float2 cc = cp[w];
                    float2 ee = WeGV[w * 10 + jk];
                    br += cc.x * ee.x - cc.y * ee.y;
                    bi += cc.x * ee.y + cc.y * ee.x;
                }
                Sp->bs[(uu * 13 + v) * 9 + jk] = make_float2(br, bi);
                rem += 64;
                if (rem >= 117) { rem -= 117; ++uu; }
            }
        }
        __syncthreads();
        // 2b: H[u0+uu][i][k] = sum_{v,j} We[v][i][j] * B[uu][v][j*3+k]
        if (t < 54) {
            int uu = t / 9, ik = t - uu * 9;
            int i = ik / 3, k = ik - i * 3;
            float hr = 0.f, hi = 0.f;
            #pragma unroll
            for (int v = 0; v < 13; ++v) {
                const float2* a = &WeGV[v * 10 + i * 3];
                const float2* b = &Sp->bs[(uu * 13 + v) * 9 + k];
                #pragma unroll
                for (int j = 0; j < 3; ++j) {
                    float2 aj = a[j];
                    float2 bj = b[j * 3];
                    hr += aj.x * bj.x - aj.y * bj.y;
                    hi += aj.x * bj.y + aj.y * bj.x;
                }
            }
            Hs[(u0 + uu) * 9 + ik] = make_float2(hr, hi);
        }
        __syncthreads();
    }

    // ---- phase 3: traces + gerelu + trnorm scales (Bs dead; union scratch)
    if (t < 12) {
        float2 a = Hs[t * 9 + 0], b = Hs[t * 9 + 4], c = Hs[t * 9 + 8];
        float2 tt = make_float2(a.x + b.x + c.x, a.y + b.y + c.y);
        Sp->s.tr1[t] = tt;
        float gg = tt.x > 0.f ? tt.x : 0.f;
        Sp->s.gb[t] = gg;
        Sp->s.tra[t] = gg * sqrtf(tt.x * tt.x + tt.y * tt.y);
    }
    __syncthreads();
    if (t < 12) {
        float m = 0.f;
        #pragma unroll
        for (int u = 0; u < 12; ++u) m += Sp->s.tra[u];
        Sp->s.sc1[t] = Sp->s.gb[t] / fmaxf(m * (1.f / 12.f), THRESH);
    }
    __syncthreads();

    // ---- phase 4: Gram values -> GV (overlays We row-major; dead now)
    for (int it = t; it < 169; it += 64) {
        float2 val;
        if (it < 156) {
            int q = it < 78 ? it : it - 78;
            float fs = sqrtf(625.0f - 8.0f * (float)q);   // exact at bucket edges
            int a = (int)((25.0f - fs) * 0.5f);
            int b = q - (a * (25 - a)) / 2 + a;
            const float2* Ha = &Hs[a * 9];
            const float2* Hb = &Hs[b * 9];
            float s = Sp->s.sc1[a] * Sp->s.sc1[b];
            float vr = 0.f, vi = 0.f;
            if (it < 78) {                    // S = tr(Aa Ab)
                #pragma unroll
                for (int i = 0; i < 3; ++i)
                    #pragma unroll
                    for (int jj = 0; jj < 3; ++jj) {
                        float2 A = Ha[i * 3 + jj], B = Hb[jj * 3 + i];
                        vr += A.x * B.x - A.y * B.y;
                        vi += A.x * B.y + A.y * B.x;
                    }
            } else {                          // Hm = tr(Aa Ab^H)
                #pragma unroll
                for (int e = 0; e < 9; ++e) {
                    float2 A = Ha[e], B = Hb[e];
                    vr += A.x * B.x + A.y * B.y;
                    vi += A.y * B.x - A.x * B.y;
                }
            }
            val = make_float2(s * vr, s * vi);
        } else if (it < 168) {
            int a = it - 156;
            float s = Sp->s.sc1[a]; float2 tt = Sp->s.tr1[a];
            val = make_float2(s * tt.x, s * tt.y);
        } else {
            val = make_float2(1.f, 0.f);
        }
        WeGV[it] = val;
    }
    __syncthreads();

    // ---- phase 5: coefficient contraction, lane=(q,u), 60 active
    //      unroll 4 -> 4 CTt/GV load pairs in flight.
    if (t < 60) {
        int q = t / 12, u = t - q * 12;
        int i0 = q * 34, i1 = (q == 4) ? 169 : i0 + 34;
        float tre = 0.f, tim = 0.f;
        #pragma unroll 4
        for (int it = i0; it < i1; ++it) {
            float4 c = CTt[it * 12 + u];
            float2 gv = WeGV[it];
            tre += c.x * gv.x + c.y * gv.y;
            tim += c.z * gv.x + c.w * gv.y;
        }
        Sp->s.tpar[u * 5 + q] = make_float2(tre, tim);
    }
    __syncthreads();

    // ---- phase 6: layer-2 gerelu + trnorm + dense head
    if (t < 12) {
        float2 tt = make_float2(0.f, 0.f);
        #pragma unroll
        for (int q = 0; q < 5; ++q) {
            float2 A = Sp->s.tpar[t * 5 + q];
            tt.x += A.x; tt.y += A.y;
        }
        Sp->s.tr1[t] = tt;
        float g = tt.x > 0.f ? tt.x : 0.f;
        Sp->s.gb[t] = g;
        Sp->s.tra[t] = g * sqrtf(tt.x * tt.x + tt.y * tt.y);
    }
    __syncthreads();
    if (t == 0) {
        float m = 0.f;
        #pragma unroll
        for (int u = 0; u < 12; ++u) m += Sp->s.tra[u];
        float inv = 1.f / fmaxf(m * (1.f / 12.f), THRESH);
        float acc = db[0];
        #pragma unroll
        for (int u = 0; u < 12; ++u) {
            float s = Sp->s.gb[u] * inv * (1.f / 3.f);
            acc += s * (Sp->s.tr1[u].x * dw[2 * u] + Sp->s.tr1[u].y * dw[2 * u + 1]);
        }
        out[p] = acc;
    }
}

extern "C" void kernel_launch(void* const* d_in, const int* in_sizes, int n_in,
                              void* d_out, int out_size, void* d_ws, size_t ws_size,
                              hipStream_t stream) {
    const float* x  = (const float*)d_in[0];
    const float* w1 = (const float*)d_in[1];
    const float* w2 = (const float*)d_in[2];
    const float* dw = (const float*)d_in[3];
    const float* db = (const float*)d_in[4];
    float* outp = (float*)d_out;
    float4* CTt = (float4*)d_ws;          // 12*169*16 B = 32448 B

    geblnet_setup<<<(12 * 169 + 255) / 256, 256, 0, stream>>>(w2, CTt);

    geblnet_main<<<NPTS / 2, 128, 0, stream>>>(
        (const float2*)x, (const float2*)w1, dw, db, CTt, outp);
}

// Round 4
// 125.373 us; speedup vs baseline: 1.0530x; 1.0530x over previous
//
#include <hip/hip_runtime.h>
#include <math.h>

// GEBLNet via Gram-matrix reduction.
// R21 = R19 structure (8192x64, 1 wave = 1 point) + per-wave LATENCY diet.
// EVIDENCE (R17-R20): residency invariant at ~11.5 waves/CU across LDS
// {8K,10K,16K} x VGPR {44,52,64} x wg-packing {1,2 waves} -> TLP is capped
// by something we cannot move; VALUBusy 60% == 1-(1-0.20)^4 with per-SIMD
// issue 20% -> latency-bound at 3 waves/SIMD. So: cut per-wave stall.
//   (a) 2a jk-thirds row caching: job=(row, jk-triple). Lane loads its 13
//       w1 float2 ONCE, reuses across 3 jk outputs: per-lane VMEM 286->104,
//       load-latency batches 22->8. We reads: 3 broadcast addrs, no conflict.
//   (b) CTt prefetch: phase-5's first 4 float4 issued before phase-4 compute
//       (no data dependence) -> phase 4 hides their L2 latency.
//   (c) Phases 3/6: width-16 __shfl_xor reductions replace LDS round-trips:
//       -2 barriers, kills serial t==0 epilogue loop.
// LESSON (R20): 2-wave wgs regress (codegen VGPR drop, no residency gain).
// LESSON (R19): ILP unroll works; VGPR 64 fine. LESSON (R18): bank conflicts
// fixed via broadcast-read layout. LESSON (R16): merged 2a+2b -> VGPR 84
// regress. LESSON (R15): fine-grained jobs beat wide. LESSON (R11): direct-w2
// contraction regresses. LESSON (R4+R7): launch_bounds min-waves arg ->
// spill. LESSON (R6): never reinterpret-cast local arrays.

#define NPTS 8192
#define THRESH 0.001f

__global__ void geblnet_setup(const float* __restrict__ w2,
                              float4* __restrict__ CTt) {
    int j = blockIdx.x * blockDim.x + threadIdx.x;
    if (j >= 12 * 169) return;
    int u = j / 169, it = j % 169;
    const float* W = w2 + u * 25 * 25 * 2;
#define WR(v, w) W[((v) * 25 + (w)) * 2]
#define WI(v, w) W[((v) * 25 + (w)) * 2 + 1]
    float c0, c1, c2, c3;
    if (it < 78) {                       // S pairs, a<=b
        int q = it, a = 0;
        while (q >= 12 - a) { q -= 12 - a; ++a; }
        int b = a + q;
        float ar = WR(a, b) + (a != b ? WR(b, a) : 0.f);
        float ai = WI(a, b) + (a != b ? WI(b, a) : 0.f);
        float br = WR(12 + a, 12 + b) + (a != b ? WR(12 + b, 12 + a) : 0.f);
        float bi = WI(12 + a, 12 + b) + (a != b ? WI(12 + b, 12 + a) : 0.f);
        c0 = ar + br; c1 = bi - ai; c2 = ai + bi; c3 = ar - br;
    } else if (it < 156) {               // Hm pairs, a<=b
        int q = it - 78, a = 0;
        while (q >= 12 - a) { q -= 12 - a; ++a; }
        int b = a + q;
        if (a != b) {
            float gr = WR(a, 12 + b) + WR(12 + b, a);
            float gi = WI(a, 12 + b) + WI(12 + b, a);
            float dr = WR(b, 12 + a) + WR(12 + a, b);
            float di = WI(b, 12 + a) + WI(12 + a, b);
            c0 = gr + dr; c1 = di - gi; c2 = gi + di; c3 = gr - dr;
        } else {
            float er = WR(a, 12 + a) + WR(12 + a, a);
            float ei = WI(a, 12 + a) + WI(12 + a, a);
            c0 = er; c1 = 0.f; c2 = ei; c3 = 0.f;
        }
    } else if (it < 168) {               // trace terms
        int a = it - 156;
        float fr = WR(a, 24) + WR(24, a), fi = WI(a, 24) + WI(24, a);
        float pr = WR(12 + a, 24) + WR(24, 12 + a);
        float pi = WI(12 + a, 24) + WI(24, 12 + a);
        c0 = fr + pr; c1 = pi - fi; c2 = fi + pi; c3 = fr - pr;
    } else {                             // unit-unit
        c0 = 3.f * WR(24, 24); c1 = 0.f; c2 = 3.f * WI(24, 24); c3 = 0.f;
    }
    CTt[it * 12 + u] = make_float4(c0, c1, c2, c3);
#undef WR
#undef WI
}

// Scratch union: Bs is dead after phase 2b; phase-3..6 scratch reuses it.
union Scr {
    float2 bs[702];                     // B[uu][v][jk], rows exact 9 (5616 B)
    struct {
        float2 tpar[60];                // phase 5 partials
        float2 tr1[12];                 // layer-1 traces (read in phase 4)
        float  sc1[12];                 // combined gerelu+trnorm scale
    } s;
};

__global__ __launch_bounds__(64) void geblnet_main(
    const float2* __restrict__ x2,      // (8192, 10, 9) complex
    const float2* __restrict__ w1g,     // (12,13,13) complex
    const float* __restrict__ dw,       // (24,)
    const float* __restrict__ db,       // (1,)
    const float4* __restrict__ CTt,     // (169,12)
    float* __restrict__ out)            // (8192,)
{
    // Overlay: phases 1-2 = We row-major (13 ch incl. identity, stride 10);
    //          phases 4-5 = GV[169].
    __shared__ float2 WeGV[170];        // 1360 B
    __shared__ Scr S;                   // 5616 B
    __shared__ float2 Hs[108];          //  864 B
    // total 7840 B -> 8192 alloc

    const int t = threadIdx.x;
    const int p = blockIdx.x;

    // ---- phase 1: build We channels 0..12, row-major only
    for (int j = t; j < 117; j += 64) {
        int v = j / 9, ik = j - v * 9;
        int i = ik / 3, jj = ik - i * 3;
        float2 val;
        if (v < 6) val = x2[(size_t)p * 90 + (4 + v) * 9 + ik];
        else if (v < 12) {
            float2 s = x2[(size_t)p * 90 + (v - 2) * 9 + jj * 3 + i];
            val = make_float2(s.x, -s.y);
        } else val = make_float2((i == jj) ? 1.f : 0.f, 0.f);
        WeGV[v * 10 + ik] = val;
    }
    __syncthreads();

    // ---- phase 2: layer 1, two u-half passes
    #pragma unroll 1
    for (int g = 0; g < 2; ++g) {
        const int u0 = g * 6;
        // 2a jk-thirds: job j = (row, jk-triple), row = (uu,v).
        //   Lane loads w1 row once (13 float2 in regs), produces 3 outputs.
        //   We reads: addr depends only on (w,d0): 3 broadcast addresses.
        #pragma unroll 1
        for (int j = t; j < 234; j += 64) {
            int row = j / 3;
            int d0 = (j - row * 3) * 3;
            int uu = row / 13;
            int v = row - uu * 13;
            const float2* cp = w1g + ((u0 + uu) * 13 + v) * 13; // contiguous
            float ar0 = 0.f, ai0 = 0.f, ar1 = 0.f, ai1 = 0.f;
            float ar2 = 0.f, ai2 = 0.f;
            #pragma unroll
            for (int w = 0; w < 13; ++w) {
                float2 cc = cp[w];
                const float2* wr = &WeGV[w * 10 + d0];
                float2 e0 = wr[0], e1 = wr[1], e2 = wr[2];
                ar0 += cc.x * e0.x - cc.y * e0.y;
                ai0 += cc.x * e0.y + cc.y * e0.x;
                ar1 += cc.x * e1.x - cc.y * e1.y;
                ai1 += cc.x * e1.y + cc.y * e1.x;
                ar2 += cc.x * e2.x - cc.y * e2.y;
                ai2 += cc.x * e2.y + cc.y * e2.x;
            }
            float2* bp = &S.bs[(uu * 13 + v) * 9 + d0];
            bp[0] = make_float2(ar0, ai0);
            bp[1] = make_float2(ar1, ai1);
            bp[2] = make_float2(ar2, ai2);
        }
        __syncthreads();
        // 2b: H[u0+uu][i][k] = sum_{v,j} We[v][i][j] * B[uu][v][j*3+k]
        if (t < 54) {
            int uu = t / 9, ik = t - uu * 9;
            int i = ik / 3, k = ik - i * 3;
            float hr = 0.f, hi = 0.f;
            #pragma unroll
            for (int v = 0; v < 13; ++v) {
                const float2* a = &WeGV[v * 10 + i * 3];
                const float2* b = &S.bs[(uu * 13 + v) * 9 + k];
                #pragma unroll
                for (int j = 0; j < 3; ++j) {
                    float2 aj = a[j];
                    float2 bj = b[j * 3];
                    hr += aj.x * bj.x - aj.y * bj.y;
                    hi += aj.x * bj.y + aj.y * bj.x;
                }
            }
            Hs[(u0 + uu) * 9 + ik] = make_float2(hr, hi);
        }
        __syncthreads();
    }

    // ---- phase 3: traces + gerelu + trnorm scales (shuffle reduce, 1 barrier)
    {
        float2 tt = make_float2(0.f, 0.f);
        float gg = 0.f, tra_v = 0.f;
        if (t < 12) {
            float2 a = Hs[t * 9 + 0], b = Hs[t * 9 + 4], c = Hs[t * 9 + 8];
            tt = make_float2(a.x + b.x + c.x, a.y + b.y + c.y);
            gg = tt.x > 0.f ? tt.x : 0.f;
            tra_v = gg * sqrtf(tt.x * tt.x + tt.y * tt.y);
        }
        float m = tra_v;                 // lanes 12..15 contribute 0
        m += __shfl_xor(m, 1, 16);
        m += __shfl_xor(m, 2, 16);
        m += __shfl_xor(m, 4, 16);
        m += __shfl_xor(m, 8, 16);
        if (t < 12) {
            S.s.tr1[t] = tt;
            S.s.sc1[t] = gg / fmaxf(m * (1.f / 12.f), THRESH);
        }
    }
    __syncthreads();

    // ---- phase 4 prologue: prefetch first 4 CTt rows for phase 5 (no dep)
    const int q5 = t / 12, u5 = t - q5 * 12;
    const int i0 = q5 * 34;
    const bool act5 = (t < 60);
    const int pbase = act5 ? i0 * 12 + u5 : 0;
    float4 pc0 = CTt[pbase];
    float4 pc1 = CTt[pbase + 12];
    float4 pc2 = CTt[pbase + 24];
    float4 pc3 = CTt[pbase + 36];

    // ---- phase 4: Gram values -> GV (overlays We row-major; dead now)
    for (int it = t; it < 169; it += 64) {
        float2 val;
        if (it < 156) {
            int q = it < 78 ? it : it - 78;
            float fs = sqrtf(625.0f - 8.0f * (float)q);   // exact at bucket edges
            int a = (int)((25.0f - fs) * 0.5f);
            int b = q - (a * (25 - a)) / 2 + a;
            const float2* Ha = &Hs[a * 9];
            const float2* Hb = &Hs[b * 9];
            float s = S.s.sc1[a] * S.s.sc1[b];
            float vr = 0.f, vi = 0.f;
            if (it < 78) {                    // S = tr(Aa Ab)
                #pragma unroll
                for (int i = 0; i < 3; ++i)
                    #pragma unroll
                    for (int jj = 0; jj < 3; ++jj) {
                        float2 A = Ha[i * 3 + jj], B = Hb[jj * 3 + i];
                        vr += A.x * B.x - A.y * B.y;
                        vi += A.x * B.y + A.y * B.x;
                    }
            } else {                          // Hm = tr(Aa Ab^H)
                #pragma unroll
                for (int e = 0; e < 9; ++e) {
                    float2 A = Ha[e], B = Hb[e];
                    vr += A.x * B.x + A.y * B.y;
                    vi += A.y * B.x - A.x * B.y;
                }
            }
            val = make_float2(s * vr, s * vi);
        } else if (it < 168) {
            int a = it - 156;
            float s = S.s.sc1[a]; float2 tt = S.s.tr1[a];
            val = make_float2(s * tt.x, s * tt.y);
        } else {
            val = make_float2(1.f, 0.f);
        }
        WeGV[it] = val;
    }
    __syncthreads();

    // ---- phase 5: coefficient contraction, lane=(q,u), 60 active
    if (act5) {
        const int i1 = (q5 == 4) ? 169 : i0 + 34;
        float2 g0 = WeGV[i0], g1 = WeGV[i0 + 1];
        float2 g2 = WeGV[i0 + 2], g3 = WeGV[i0 + 3];
        float tre = pc0.x * g0.x + pc0.y * g0.y
                  + pc1.x * g1.x + pc1.y * g1.y
                  + pc2.x * g2.x + pc2.y * g2.y
                  + pc3.x * g3.x + pc3.y * g3.y;
        float tim = pc0.z * g0.x + pc0.w * g0.y
                  + pc1.z * g1.x + pc1.w * g1.y
                  + pc2.z * g2.x + pc2.w * g2.y
                  + pc3.z * g3.x + pc3.w * g3.y;
        #pragma unroll 4
        for (int it = i0 + 4; it < i1; ++it) {
            float4 c = CTt[it * 12 + u5];
            float2 gv = WeGV[it];
            tre += c.x * gv.x + c.y * gv.y;
            tim += c.z * gv.x + c.w * gv.y;
        }
        S.s.tpar[u5 * 5 + q5] = make_float2(tre, tim);
    }
    __syncthreads();

    // ---- phase 6: layer-2 gerelu + trnorm + dense head (shuffle, 0 barrier)
    {
        float2 tt = make_float2(0.f, 0.f);
        float gg = 0.f, tra_v = 0.f;
        if (t < 12) {
            #pragma unroll
            for (int q = 0; q < 5; ++q) {
                float2 A = S.s.tpar[t * 5 + q];
                tt.x += A.x; tt.y += A.y;
            }
            gg = tt.x > 0.f ? tt.x : 0.f;
            tra_v = gg * sqrtf(tt.x * tt.x + tt.y * tt.y);
        }
        float m = tra_v;                 // lanes 12..15 contribute 0
        m += __shfl_xor(m, 1, 16);
        m += __shfl_xor(m, 2, 16);
        m += __shfl_xor(m, 4, 16);
        m += __shfl_xor(m, 8, 16);
        float term = 0.f;
        if (t < 12) {
            float inv = 1.f / fmaxf(m * (1.f / 12.f), THRESH);
            float s = gg * inv * (1.f / 3.f);
            term = s * (tt.x * dw[2 * t] + tt.y * dw[2 * t + 1]);
        }
        term += __shfl_xor(term, 1, 16);
        term += __shfl_xor(term, 2, 16);
        term += __shfl_xor(term, 4, 16);
        term += __shfl_xor(term, 8, 16);
        if (t == 0) out[p] = term + db[0];
    }
}

extern "C" void kernel_launch(void* const* d_in, const int* in_sizes, int n_in,
                              void* d_out, int out_size, void* d_ws, size_t ws_size,
                              hipStream_t stream) {
    const float* x  = (const float*)d_in[0];
    const float* w1 = (const float*)d_in[1];
    const float* w2 = (const float*)d_in[2];
    const float* dw = (const float*)d_in[3];
    const float* db = (const float*)d_in[4];
    float* outp = (float*)d_out;
    float4* CTt = (float4*)d_ws;          // 12*169*16 B = 32448 B

    geblnet_setup<<<(12 * 169 + 255) / 256, 256, 0, stream>>>(w2, CTt);

    geblnet_main<<<NPTS, 64, 0, stream>>>(
        (const float2*)x, (const float2*)w1, dw, db, CTt, outp);
}